// Round 1
// baseline (1029.805 us; speedup 1.0000x reference)
//
#include <hip/hip_runtime.h>
#include <hip/hip_bf16.h>
#include <math.h>

#define NN 100000
#define EE 800000

static constexpr int SCAN_CH = 512;
static constexpr int NCH = (NN + SCAN_CH - 1) / SCAN_CH; // 196

__device__ __forceinline__ float leaky(float a) { return a >= 0.0f ? a : 0.2f * a; }
__device__ __forceinline__ float quantize(float v, float s) {
    float r = rintf(v / s);
    r = fminf(fmaxf(r, -128.0f), 127.0f);
    return r * s;
}

// ---------------- init: zero counters ----------------
__global__ void k_init(unsigned* deg_src, unsigned* deg_dst, unsigned* s1, unsigned* s2) {
    int i = blockIdx.x * 256 + threadIdx.x;
    if (i < NN) { deg_src[i] = 0; deg_dst[i] = 0; }
    if (i < 256) { s1[i] = 0; s2[i] = 0; }
}

// ---------------- degree count ----------------
__global__ void k_deg(const int* ei, unsigned* deg_src, unsigned* deg_dst) {
    int e = blockIdx.x * 256 + threadIdx.x;
    if (e < EE) {
        atomicAdd(&deg_src[ei[e]], 1u);
        atomicAdd(&deg_dst[ei[EE + e]], 1u);
    }
}

// ---------------- scan (3 kernels) ----------------
__global__ void k_scan_chunksum(const unsigned* deg_dst, unsigned* chunkSum) {
    __shared__ unsigned red[256];
    int b = blockIdx.x, t = threadIdx.x;
    int g0 = b * SCAN_CH + t;
    unsigned v = 0;
    if (g0 < NN) v += deg_dst[g0];
    if (g0 + 256 < NN && t + 256 < SCAN_CH) v += deg_dst[g0 + 256];
    red[t] = v; __syncthreads();
    for (int s = 128; s > 0; s >>= 1) { if (t < s) red[t] += red[t + s]; __syncthreads(); }
    if (t == 0) chunkSum[b] = red[0];
}

__global__ void k_scan_chunkoff(const unsigned* chunkSum, unsigned* chunkOff, unsigned* off) {
    __shared__ unsigned sc[256];
    int t = threadIdx.x;
    unsigned v = (t < NCH) ? chunkSum[t] : 0u;
    sc[t] = v; __syncthreads();
    for (int d = 1; d < 256; d <<= 1) {
        unsigned add = (t >= d) ? sc[t - d] : 0u; __syncthreads();
        sc[t] += add; __syncthreads();
    }
    if (t < NCH) chunkOff[t] = sc[t] - v;
    if (t == 255) off[NN] = sc[255];
}

__global__ void k_scan_final(const unsigned* deg_dst, const unsigned* chunkOff,
                             unsigned* off, unsigned* cursor) {
    __shared__ unsigned sc[256];
    int b = blockIdx.x, t = threadIdx.x;
    int g0 = b * SCAN_CH + 2 * t;
    unsigned a = (g0 < NN) ? deg_dst[g0] : 0u;
    unsigned c = (g0 + 1 < NN) ? deg_dst[g0 + 1] : 0u;
    unsigned ps = a + c;
    sc[t] = ps; __syncthreads();
    for (int d = 1; d < 256; d <<= 1) {
        unsigned add = (t >= d) ? sc[t - d] : 0u; __syncthreads();
        sc[t] += add; __syncthreads();
    }
    unsigned base = chunkOff[b] + sc[t] - ps;
    if (g0 < NN)     { off[g0] = base;         cursor[g0] = base; }
    if (g0 + 1 < NN) { off[g0 + 1] = base + a; cursor[g0 + 1] = base + a; }
}

// ---------------- scatter: sort edges by dst ----------------
__global__ void k_scatter(const int* ei, unsigned* cursor, unsigned* perm, unsigned* src_sorted) {
    int e = blockIdx.x * 256 + threadIdx.x;
    if (e < EE) {
        int d = ei[EE + e];
        unsigned pos = atomicAdd(&cursor[d], 1u);
        perm[pos] = (unsigned)e;
        src_sorted[pos] = (unsigned)ei[e];
    }
}

// ---------------- degree norm tables ----------------
__global__ void k_rnorm(const unsigned* deg_src, const float* a1p, const float* a2p,
                        float* rn1, float* rn2) {
    int n = blockIdx.x * 256 + threadIdx.x;
    if (n < NN) {
        float d = (float)deg_src[n] + 1.0f;
        rn1[n] = powf(d, -a1p[0]);
        rn2[n] = powf(d, -a2p[0]);
    }
}

// ---------------- weight fake-quant + a_edge projection vectors ----------------
__global__ void k_weights(const float* W1, const float* W2,
                          const float* We1, const float* ae1,
                          const float* We2, const float* ae2,
                          float* Wq1, float* Wq2, float* v1, float* v2) {
    __shared__ float red[256];
    int t = threadIdx.x;
    float m = 0.0f;
    for (int i = t; i < 8192; i += 256) m = fmaxf(m, fabsf(W1[i]));
    red[t] = m; __syncthreads();
    for (int s = 128; s > 0; s >>= 1) { if (t < s) red[t] = fmaxf(red[t], red[t + s]); __syncthreads(); }
    float s1 = fmaxf(red[0], 1e-8f) / 127.0f;
    __syncthreads();
    for (int i = t; i < 8192; i += 256) Wq1[i] = quantize(W1[i], s1);

    m = 0.0f;
    for (int i = t; i < 8192; i += 256) m = fmaxf(m, fabsf(W2[i]));
    red[t] = m; __syncthreads();
    for (int s = 128; s > 0; s >>= 1) { if (t < s) red[t] = fmaxf(red[t], red[t + s]); __syncthreads(); }
    float s2 = fmaxf(red[0], 1e-8f) / 127.0f;
    __syncthreads();
    for (int i = t; i < 8192; i += 256) Wq2[i] = quantize(W2[i], s2);

    if (t < 64) {
        int h = t >> 5, d = t & 31;
        float acc = 0.0f;
        for (int c = 0; c < 64; ++c) acc += We1[(h * 64 + c) * 32 + d] * ae1[h * 64 + c];
        v1[t] = acc;
    } else if (t < 128) {
        int tt = t - 64; int h = tt >> 5, d = tt & 31;
        float acc = 0.0f;
        for (int c = 0; c < 64; ++c) acc += We2[(h * 64 + c) * 32 + d] * ae2[h * 64 + c];
        v2[tt] = acc;
    }
}

// ---------------- a_edge for both layers in one edge_attr pass ----------------
__global__ void k_aedge(const float* edge_attr, const float* v1, const float* v2,
                        float2* ae1o, float2* ae2o) {
    __shared__ float vs[128];
    int t = threadIdx.x;
    if (t < 64) vs[t] = v1[t];
    else if (t < 128) vs[t] = v2[t - 64];
    __syncthreads();
    int e = blockIdx.x * 256 + t;
    if (e >= EE) return;
    const float4* ea = (const float4*)(edge_attr + (size_t)e * 32);
    float a00 = 0, a01 = 0, a10 = 0, a11 = 0;
#pragma unroll
    for (int q = 0; q < 8; ++q) {
        float4 w = ea[q];
        float xs[4] = {w.x, w.y, w.z, w.w};
#pragma unroll
        for (int j = 0; j < 4; ++j) {
            int d = q * 4 + j;
            a00 += xs[j] * vs[d];
            a01 += xs[j] * vs[32 + d];
            a10 += xs[j] * vs[64 + d];
            a11 += xs[j] * vs[96 + d];
        }
    }
    ae1o[e] = make_float2(a00, a01);
    ae2o[e] = make_float2(a10, a11);
}

// ---------------- h = xn @ Wq.T  (+ a_src, a_dst dots), wave per node ----------------
__global__ void k_hproj(const float* __restrict__ in, const float* __restrict__ rn,
                        const float* __restrict__ Wq,
                        const float* __restrict__ att_s, const float* __restrict__ att_d,
                        float* __restrict__ hout, float2* __restrict__ asrc,
                        float2* __restrict__ adst) {
    __shared__ float wl[128 * 65];
    int t = threadIdx.x;
    for (int i = t; i < 8192; i += 256) {
        int r = i >> 6, c = i & 63;
        wl[r * 65 + c] = Wq[i];
    }
    int l = t & 63;
    float as0 = att_s[l], as1 = att_s[64 + l];
    float ad0 = att_d[l], ad1 = att_d[64 + l];
    __syncthreads();
    int node = blockIdx.x * 4 + (t >> 6);
    if (node >= NN) return;
    float xv = in[(size_t)node * 64 + l];
    if (rn) xv *= rn[node];
    float acc0 = 0.0f, acc1 = 0.0f;
#pragma unroll
    for (int k = 0; k < 64; ++k) {
        float xk = __shfl(xv, k, 64);
        acc0 += xk * wl[l * 65 + k];
        acc1 += xk * wl[(64 + l) * 65 + k];
    }
    hout[(size_t)node * 128 + l] = acc0;
    hout[(size_t)node * 128 + 64 + l] = acc1;
    float p0 = acc0 * as0, p1 = acc1 * as1, p2 = acc0 * ad0, p3 = acc1 * ad1;
#pragma unroll
    for (int m = 32; m > 0; m >>= 1) {
        p0 += __shfl_xor(p0, m, 64);
        p1 += __shfl_xor(p1, m, 64);
        p2 += __shfl_xor(p2, m, 64);
        p3 += __shfl_xor(p3, m, 64);
    }
    if (l == 0) {
        asrc[node] = make_float2(p0, p1);
        adst[node] = make_float2(p2, p3);
    }
}

// ---------------- softmax + aggregate, wave per destination node ----------------
__global__ void k_aggregate(const unsigned* __restrict__ off, const unsigned* __restrict__ src_sorted,
                            const unsigned* __restrict__ perm,
                            const float2* __restrict__ asrc, const float2* __restrict__ adst,
                            const float2* __restrict__ aeL,
                            const float* __restrict__ h, const float* __restrict__ bias,
                            float* __restrict__ outp, unsigned* __restrict__ amax_slots) {
    int t = threadIdx.x;
    int l = t & 63;
    int node = blockIdx.x * 4 + (t >> 6);
    if (node >= NN) return;
    unsigned s0 = off[node], e0 = off[node + 1];
    float2 adv = adst[node];
    float m0 = -INFINITY, m1 = -INFINITY;
    for (unsigned base = s0; base < e0; base += 64) {
        unsigned i = base + l;
        float a0 = -INFINITY, a1 = -INFINITY;
        if (i < e0) {
            unsigned s = src_sorted[i], p = perm[i];
            float2 av = asrc[s]; float2 ev = aeL[p];
            a0 = leaky(av.x + adv.x + ev.x);
            a1 = leaky(av.y + adv.y + ev.y);
        }
        m0 = fmaxf(m0, a0); m1 = fmaxf(m1, a1);
    }
#pragma unroll
    for (int m = 32; m > 0; m >>= 1) {
        m0 = fmaxf(m0, __shfl_xor(m0, m, 64));
        m1 = fmaxf(m1, __shfl_xor(m1, m, 64));
    }
    float acc0 = 0.0f, acc1 = 0.0f, sum0 = 0.0f, sum1 = 0.0f;
    for (unsigned i = s0; i < e0; ++i) {
        unsigned s = src_sorted[i], p = perm[i];
        float2 av = asrc[s]; float2 ev = aeL[p];
        float p0 = __expf(leaky(av.x + adv.x + ev.x) - m0);
        float p1 = __expf(leaky(av.y + adv.y + ev.y) - m1);
        sum0 += p0; sum1 += p1;
        const float* hr = h + (size_t)s * 128;
        acc0 += p0 * hr[l];
        acc1 += p1 * hr[64 + l];
    }
    float o = 0.5f * (acc0 / (sum0 + 1e-16f) + acc1 / (sum1 + 1e-16f)) + bias[l];
    outp[(size_t)node * 64 + l] = o;
    float v = fabsf(o);
#pragma unroll
    for (int m = 32; m > 0; m >>= 1) v = fmaxf(v, __shfl_xor(v, m, 64));
    if (l == 0) atomicMax(&amax_slots[node & 255], __float_as_uint(v));
}

// ---------------- reduce 256 absmax slots -> scale ----------------
__global__ void k_amax_reduce(const unsigned* slots, float* s_out) {
    __shared__ unsigned red[256];
    int t = threadIdx.x;
    red[t] = slots[t]; __syncthreads();
    for (int s = 128; s > 0; s >>= 1) {
        if (t < s) red[t] = (red[t] > red[t + s]) ? red[t] : red[t + s];
        __syncthreads();
    }
    if (t == 0) s_out[0] = fmaxf(__uint_as_float(red[0]), 1e-8f) / 127.0f;
}

// ---------------- quant + relu + degree-norm (layer1 -> layer2 input) ----------------
__global__ void k_quant_relu_norm(float* buf, const float* s_in, const float* rn2) {
    int i = blockIdx.x * 256 + threadIdx.x;
    if (i >= NN * 64) return;
    float s = s_in[0];
    float q = quantize(buf[i], s);
    buf[i] = fmaxf(q, 0.0f) * rn2[i >> 6];
}

// ---------------- final output fake-quant in place ----------------
__global__ void k_quant_out(float* buf, const float* s_in) {
    int i = blockIdx.x * 256 + threadIdx.x;
    if (i >= NN * 64) return;
    buf[i] = quantize(buf[i], s_in[0]);
}

extern "C" void kernel_launch(void* const* d_in, const int* in_sizes, int n_in,
                              void* d_out, int out_size, void* d_ws, size_t ws_size,
                              hipStream_t stream) {
    const float* x     = (const float*)d_in[0];
    const int*   ei    = (const int*)d_in[1];
    const float* eattr = (const float*)d_in[2];
    const float* a1    = (const float*)d_in[3];
    const float* W1    = (const float*)d_in[4];
    const float* We1   = (const float*)d_in[5];
    const float* as1   = (const float*)d_in[6];
    const float* ad1   = (const float*)d_in[7];
    const float* ae1   = (const float*)d_in[8];
    const float* b1    = (const float*)d_in[9];
    const float* a2    = (const float*)d_in[10];
    const float* W2    = (const float*)d_in[11];
    const float* We2   = (const float*)d_in[12];
    const float* as2   = (const float*)d_in[13];
    const float* ad2   = (const float*)d_in[14];
    const float* ae2   = (const float*)d_in[15];
    const float* b2    = (const float*)d_in[16];
    float* out = (float*)d_out;

    char* w = (char*)d_ws;
    size_t o = 0;
    auto alloc = [&](size_t bytes) -> char* {
        char* p = w + o;
        o += (bytes + 255) & ~(size_t)255;
        return p;
    };
    unsigned* deg_src  = (unsigned*)alloc((size_t)NN * 4);
    unsigned* deg_dst  = (unsigned*)alloc((size_t)NN * 4);
    unsigned* offs     = (unsigned*)alloc((size_t)(NN + 1) * 4);
    unsigned* cursor   = (unsigned*)alloc((size_t)NN * 4);
    unsigned* chunkSum = (unsigned*)alloc((size_t)NCH * 4);
    unsigned* chunkOff = (unsigned*)alloc((size_t)NCH * 4);
    unsigned* perm     = (unsigned*)alloc((size_t)EE * 4);
    unsigned* src_s    = (unsigned*)alloc((size_t)EE * 4);
    float2*   aeg1     = (float2*)alloc((size_t)EE * 8);
    float2*   aeg2     = (float2*)alloc((size_t)EE * 8);
    float2*   asrc     = (float2*)alloc((size_t)NN * 8);
    float2*   adst     = (float2*)alloc((size_t)NN * 8);
    float*    hbuf     = (float*)alloc((size_t)NN * 128 * 4);
    float*    mid      = (float*)alloc((size_t)NN * 64 * 4);
    float*    rn1      = (float*)alloc((size_t)NN * 4);
    float*    rn2      = (float*)alloc((size_t)NN * 4);
    float*    Wq1      = (float*)alloc(8192 * 4);
    float*    Wq2      = (float*)alloc(8192 * 4);
    float*    v1       = (float*)alloc(64 * 4);
    float*    v2       = (float*)alloc(64 * 4);
    unsigned* slots1   = (unsigned*)alloc(256 * 4);
    unsigned* slots2   = (unsigned*)alloc(256 * 4);
    float*    s1       = (float*)alloc(4);
    float*    s2       = (float*)alloc(4);

    dim3 B(256);
    k_init<<<391, B, 0, stream>>>(deg_src, deg_dst, slots1, slots2);
    k_deg<<<3125, B, 0, stream>>>(ei, deg_src, deg_dst);
    k_scan_chunksum<<<NCH, B, 0, stream>>>(deg_dst, chunkSum);
    k_scan_chunkoff<<<1, B, 0, stream>>>(chunkSum, chunkOff, offs);
    k_scan_final<<<NCH, B, 0, stream>>>(deg_dst, chunkOff, offs, cursor);
    k_scatter<<<3125, B, 0, stream>>>(ei, cursor, perm, src_s);
    k_rnorm<<<391, B, 0, stream>>>(deg_src, a1, a2, rn1, rn2);
    k_weights<<<1, B, 0, stream>>>(W1, W2, We1, ae1, We2, ae2, Wq1, Wq2, v1, v2);
    k_aedge<<<3125, B, 0, stream>>>(eattr, v1, v2, aeg1, aeg2);
    // layer 1
    k_hproj<<<25000, B, 0, stream>>>(x, rn1, Wq1, as1, ad1, hbuf, asrc, adst);
    k_aggregate<<<25000, B, 0, stream>>>(offs, src_s, perm, asrc, adst, aeg1, hbuf, b1, mid, slots1);
    k_amax_reduce<<<1, B, 0, stream>>>(slots1, s1);
    k_quant_relu_norm<<<25000, B, 0, stream>>>(mid, s1, rn2);
    // layer 2
    k_hproj<<<25000, B, 0, stream>>>(mid, nullptr, Wq2, as2, ad2, hbuf, asrc, adst);
    k_aggregate<<<25000, B, 0, stream>>>(offs, src_s, perm, asrc, adst, aeg2, hbuf, b2, out, slots2);
    k_amax_reduce<<<1, B, 0, stream>>>(slots2, s2);
    k_quant_out<<<25000, B, 0, stream>>>(out, s2);
}

// Round 2
// 872.333 us; speedup vs baseline: 1.1805x; 1.1805x over previous
//
#include <hip/hip_runtime.h>
#include <hip/hip_bf16.h>
#include <math.h>

#define NN 100000
#define EE 800000

static constexpr int SCAN_CH = 512;
static constexpr int NCH = (NN + SCAN_CH - 1) / SCAN_CH; // 196

__device__ __forceinline__ float leaky(float a) { return a >= 0.0f ? a : 0.2f * a; }
__device__ __forceinline__ float quantize(float v, float s) {
    float r = rintf(v / s);
    r = fminf(fmaxf(r, -128.0f), 127.0f);
    return r * s;
}

// ---------------- init: zero counters ----------------
__global__ void k_init(unsigned* deg_src, unsigned* deg_dst, unsigned* s1, unsigned* s2) {
    int i = blockIdx.x * 256 + threadIdx.x;
    if (i < NN) { deg_src[i] = 0; deg_dst[i] = 0; }
    if (i < 256) { s1[i] = 0; s2[i] = 0; }
}

// ---------------- degree count ----------------
__global__ void k_deg(const int* ei, unsigned* deg_src, unsigned* deg_dst) {
    int e = blockIdx.x * 256 + threadIdx.x;
    if (e < EE) {
        atomicAdd(&deg_src[ei[e]], 1u);
        atomicAdd(&deg_dst[ei[EE + e]], 1u);
    }
}

// ---------------- scan (3 kernels) ----------------
__global__ void k_scan_chunksum(const unsigned* deg_dst, unsigned* chunkSum) {
    __shared__ unsigned red[256];
    int b = blockIdx.x, t = threadIdx.x;
    int g0 = b * SCAN_CH + t;
    unsigned v = 0;
    if (g0 < NN) v += deg_dst[g0];
    if (g0 + 256 < NN && t + 256 < SCAN_CH) v += deg_dst[g0 + 256];
    red[t] = v; __syncthreads();
    for (int s = 128; s > 0; s >>= 1) { if (t < s) red[t] += red[t + s]; __syncthreads(); }
    if (t == 0) chunkSum[b] = red[0];
}

__global__ void k_scan_chunkoff(const unsigned* chunkSum, unsigned* chunkOff, unsigned* off) {
    __shared__ unsigned sc[256];
    int t = threadIdx.x;
    unsigned v = (t < NCH) ? chunkSum[t] : 0u;
    sc[t] = v; __syncthreads();
    for (int d = 1; d < 256; d <<= 1) {
        unsigned add = (t >= d) ? sc[t - d] : 0u; __syncthreads();
        sc[t] += add; __syncthreads();
    }
    if (t < NCH) chunkOff[t] = sc[t] - v;
    if (t == 255) off[NN] = sc[255];
}

__global__ void k_scan_final(const unsigned* deg_dst, const unsigned* chunkOff,
                             unsigned* off, unsigned* cursor) {
    __shared__ unsigned sc[256];
    int b = blockIdx.x, t = threadIdx.x;
    int g0 = b * SCAN_CH + 2 * t;
    unsigned a = (g0 < NN) ? deg_dst[g0] : 0u;
    unsigned c = (g0 + 1 < NN) ? deg_dst[g0 + 1] : 0u;
    unsigned ps = a + c;
    sc[t] = ps; __syncthreads();
    for (int d = 1; d < 256; d <<= 1) {
        unsigned add = (t >= d) ? sc[t - d] : 0u; __syncthreads();
        sc[t] += add; __syncthreads();
    }
    unsigned base = chunkOff[b] + sc[t] - ps;
    if (g0 < NN)     { off[g0] = base;         cursor[g0] = base; }
    if (g0 + 1 < NN) { off[g0 + 1] = base + a; cursor[g0 + 1] = base + a; }
}

// ---------------- scatter: sort edges by dst ----------------
__global__ void k_scatter(const int* ei, unsigned* cursor, unsigned* pos_of_edge,
                          unsigned* src_sorted, unsigned* dst_sorted) {
    int e = blockIdx.x * 256 + threadIdx.x;
    if (e < EE) {
        int d = ei[EE + e];
        unsigned pos = atomicAdd(&cursor[d], 1u);
        pos_of_edge[e] = pos;
        src_sorted[pos] = (unsigned)ei[e];
        dst_sorted[pos] = (unsigned)d;
    }
}

// ---------------- degree norm tables ----------------
__global__ void k_rnorm(const unsigned* deg_src, const float* a1p, const float* a2p,
                        float* rn1, float* rn2) {
    int n = blockIdx.x * 256 + threadIdx.x;
    if (n < NN) {
        float d = (float)deg_src[n] + 1.0f;
        rn1[n] = powf(d, -a1p[0]);
        rn2[n] = powf(d, -a2p[0]);
    }
}

// ---------------- weight fake-quant + a_edge projection vectors ----------------
__global__ void k_weights(const float* W1, const float* W2,
                          const float* We1, const float* ae1,
                          const float* We2, const float* ae2,
                          float* Wq1, float* Wq2, float* v1, float* v2) {
    __shared__ float red[256];
    int t = threadIdx.x;
    float m = 0.0f;
    for (int i = t; i < 8192; i += 256) m = fmaxf(m, fabsf(W1[i]));
    red[t] = m; __syncthreads();
    for (int s = 128; s > 0; s >>= 1) { if (t < s) red[t] = fmaxf(red[t], red[t + s]); __syncthreads(); }
    float s1 = fmaxf(red[0], 1e-8f) / 127.0f;
    __syncthreads();
    for (int i = t; i < 8192; i += 256) Wq1[i] = quantize(W1[i], s1);

    m = 0.0f;
    for (int i = t; i < 8192; i += 256) m = fmaxf(m, fabsf(W2[i]));
    red[t] = m; __syncthreads();
    for (int s = 128; s > 0; s >>= 1) { if (t < s) red[t] = fmaxf(red[t], red[t + s]); __syncthreads(); }
    float s2 = fmaxf(red[0], 1e-8f) / 127.0f;
    __syncthreads();
    for (int i = t; i < 8192; i += 256) Wq2[i] = quantize(W2[i], s2);

    if (t < 64) {
        int h = t >> 5, d = t & 31;
        float acc = 0.0f;
        for (int c = 0; c < 64; ++c) acc += We1[(h * 64 + c) * 32 + d] * ae1[h * 64 + c];
        v1[t] = acc;
    } else if (t < 128) {
        int tt = t - 64; int h = tt >> 5, d = tt & 31;
        float acc = 0.0f;
        for (int c = 0; c < 64; ++c) acc += We2[(h * 64 + c) * 32 + d] * ae2[h * 64 + c];
        v2[tt] = acc;
    }
}

// ---------------- a_edge for both layers, written in dst-sorted order ----------------
__global__ void k_aedge(const float* edge_attr, const float* v1, const float* v2,
                        const unsigned* pos_of_edge, float2* ae1s, float2* ae2s) {
    __shared__ float vs[128];
    int t = threadIdx.x;
    if (t < 64) vs[t] = v1[t];
    else if (t < 128) vs[t] = v2[t - 64];
    __syncthreads();
    int e = blockIdx.x * 256 + t;
    if (e >= EE) return;
    const float4* ea = (const float4*)(edge_attr + (size_t)e * 32);
    float a00 = 0, a01 = 0, a10 = 0, a11 = 0;
#pragma unroll
    for (int q = 0; q < 8; ++q) {
        float4 w = ea[q];
        float xs4[4] = {w.x, w.y, w.z, w.w};
#pragma unroll
        for (int j = 0; j < 4; ++j) {
            int d = q * 4 + j;
            a00 += xs4[j] * vs[d];
            a01 += xs4[j] * vs[32 + d];
            a10 += xs4[j] * vs[64 + d];
            a11 += xs4[j] * vs[96 + d];
        }
    }
    unsigned pos = pos_of_edge[e];
    ae1s[pos] = make_float2(a00, a01);
    ae2s[pos] = make_float2(a10, a11);
}

// ---------------- h = xn @ Wq.T (+ a_src/a_dst dots) ----------------
// W rows in VGPRs (one output column per lane), x tile broadcast from LDS.
__global__ void k_hproj(const float* __restrict__ in, const float* __restrict__ rn,
                        const float* __restrict__ Wq,
                        const float* __restrict__ att_s, const float* __restrict__ att_d,
                        float* __restrict__ hout, float* __restrict__ asrc,
                        float* __restrict__ adst) {
    __shared__ float xs[32][64];   // 8 KB: 32 nodes x 64 features
    int t = threadIdx.x;
    int node0 = blockIdx.x * 32;
    // stage x tile (rn-scaled), 2 float4 per thread
    for (int i = t; i < 512; i += 256) {
        int n = i >> 4, c4 = i & 15;
        int node = node0 + n;
        float4 v = make_float4(0.f, 0.f, 0.f, 0.f);
        if (node < NN) {
            v = ((const float4*)(in + (size_t)node * 64))[c4];
            if (rn) { float r = rn[node]; v.x *= r; v.y *= r; v.z *= r; v.w *= r; }
        }
        ((float4*)xs[n])[c4] = v;
    }
    int w = t >> 6, l = t & 63;
    int out = ((w & 1) << 6) | l;          // 0..127; wave covers one full head
    float4 wr[16];
    const float4* wp = (const float4*)(Wq + (size_t)out * 64);
#pragma unroll
    for (int q = 0; q < 16; ++q) wr[q] = wp[q];
    float ats = att_s[out], atd = att_d[out];
    __syncthreads();
    int nbase = (w >> 1) * 16;             // waves {0,1}: nodes 0..15, {2,3}: 16..31
    for (int nn = 0; nn < 16; ++nn) {
        int node = node0 + nbase + nn;
        if (node >= NN) break;
        const float4* xr = (const float4*)xs[nbase + nn];
        float acc = 0.0f;
#pragma unroll
        for (int q = 0; q < 16; ++q) {
            float4 xv = xr[q];             // uniform address -> LDS broadcast
            float4 wv = wr[q];
            acc += xv.x * wv.x + xv.y * wv.y + xv.z * wv.z + xv.w * wv.w;
        }
        hout[(size_t)node * 128 + out] = acc;
        float ps = acc * ats, pd = acc * atd;
#pragma unroll
        for (int m = 32; m > 0; m >>= 1) {
            ps += __shfl_xor(ps, m, 64);
            pd += __shfl_xor(pd, m, 64);
        }
        if (l == 0) {
            int head = w & 1;
            asrc[(size_t)node * 2 + head] = ps;
            adst[(size_t)node * 2 + head] = pd;
        }
    }
}

// ---------------- edge-parallel: p = exp(leaky(a_src+a_dst+a_edge)), sorted order ----------------
__global__ void k_alphap(const unsigned* __restrict__ src_s, const unsigned* __restrict__ dst_s,
                         const float* __restrict__ asrc, const float* __restrict__ adst,
                         const float2* __restrict__ aes, float2* __restrict__ ap) {
    int i = blockIdx.x * 256 + threadIdx.x;
    if (i >= EE) return;
    unsigned s = src_s[i], d = dst_s[i];
    float2 av = ((const float2*)asrc)[s];
    float2 dv = ((const float2*)adst)[d];
    float2 ev = aes[i];
    float a0 = leaky(av.x + dv.x + ev.x);
    float a1 = leaky(av.y + dv.y + ev.y);
    ap[i] = make_float2(__expf(a0), __expf(a1));
}

// ---------------- aggregate: wave per destination node, single pass ----------------
__global__ void k_aggregate(const unsigned* __restrict__ off, const unsigned* __restrict__ src_s,
                            const float2* __restrict__ ap,
                            const float* __restrict__ h, const float* __restrict__ bias,
                            float* __restrict__ outp, unsigned* __restrict__ amax_slots) {
    int t = threadIdx.x;
    int l = t & 63;
    int node = blockIdx.x * 4 + (t >> 6);
    if (node >= NN) return;
    unsigned s0 = off[node], e0 = off[node + 1];
    float acc0 = 0.f, acc1 = 0.f, sum0 = 0.f, sum1 = 0.f;
    if (s0 < e0) {
        unsigned s_c = src_s[s0];
        float2 p_c = ap[s0];
        float h0c = h[(size_t)s_c * 128 + l];
        float h1c = h[(size_t)s_c * 128 + 64 + l];
        for (unsigned i = s0 + 1; i < e0; ++i) {
            unsigned s_n = src_s[i];
            float2 p_n = ap[i];
            float h0n = h[(size_t)s_n * 128 + l];
            float h1n = h[(size_t)s_n * 128 + 64 + l];
            sum0 += p_c.x; sum1 += p_c.y;
            acc0 = fmaf(p_c.x, h0c, acc0);
            acc1 = fmaf(p_c.y, h1c, acc1);
            p_c = p_n; h0c = h0n; h1c = h1n;
        }
        sum0 += p_c.x; sum1 += p_c.y;
        acc0 = fmaf(p_c.x, h0c, acc0);
        acc1 = fmaf(p_c.y, h1c, acc1);
    }
    float o = 0.5f * (acc0 / (sum0 + 1e-16f) + acc1 / (sum1 + 1e-16f)) + bias[l];
    outp[(size_t)node * 64 + l] = o;
    float v = fabsf(o);
#pragma unroll
    for (int m = 32; m > 0; m >>= 1) v = fmaxf(v, __shfl_xor(v, m, 64));
    if (l == 0) atomicMax(&amax_slots[node & 255], __float_as_uint(v));
}

// ---------------- reduce 256 absmax slots -> scale ----------------
__global__ void k_amax_reduce(const unsigned* slots, float* s_out) {
    __shared__ unsigned red[256];
    int t = threadIdx.x;
    red[t] = slots[t]; __syncthreads();
    for (int s = 128; s > 0; s >>= 1) {
        if (t < s) red[t] = (red[t] > red[t + s]) ? red[t] : red[t + s];
        __syncthreads();
    }
    if (t == 0) s_out[0] = fmaxf(__uint_as_float(red[0]), 1e-8f) / 127.0f;
}

// ---------------- quant + relu + degree-norm (layer1 -> layer2 input) ----------------
__global__ void k_quant_relu_norm(float* buf, const float* s_in, const float* rn2) {
    int i = blockIdx.x * 256 + threadIdx.x;
    if (i >= NN * 64) return;
    float s = s_in[0];
    float q = quantize(buf[i], s);
    buf[i] = fmaxf(q, 0.0f) * rn2[i >> 6];
}

// ---------------- final output fake-quant in place ----------------
__global__ void k_quant_out(float* buf, const float* s_in) {
    int i = blockIdx.x * 256 + threadIdx.x;
    if (i >= NN * 64) return;
    buf[i] = quantize(buf[i], s_in[0]);
}

extern "C" void kernel_launch(void* const* d_in, const int* in_sizes, int n_in,
                              void* d_out, int out_size, void* d_ws, size_t ws_size,
                              hipStream_t stream) {
    const float* x     = (const float*)d_in[0];
    const int*   ei    = (const int*)d_in[1];
    const float* eattr = (const float*)d_in[2];
    const float* a1    = (const float*)d_in[3];
    const float* W1    = (const float*)d_in[4];
    const float* We1   = (const float*)d_in[5];
    const float* as1   = (const float*)d_in[6];
    const float* ad1   = (const float*)d_in[7];
    const float* ae1   = (const float*)d_in[8];
    const float* b1    = (const float*)d_in[9];
    const float* a2    = (const float*)d_in[10];
    const float* W2    = (const float*)d_in[11];
    const float* We2   = (const float*)d_in[12];
    const float* as2   = (const float*)d_in[13];
    const float* ad2   = (const float*)d_in[14];
    const float* ae2   = (const float*)d_in[15];
    const float* b2    = (const float*)d_in[16];
    float* out = (float*)d_out;

    char* w = (char*)d_ws;
    size_t o = 0;
    auto alloc = [&](size_t bytes) -> char* {
        char* p = w + o;
        o += (bytes + 255) & ~(size_t)255;
        return p;
    };
    unsigned* deg_src  = (unsigned*)alloc((size_t)NN * 4);
    unsigned* deg_dst  = (unsigned*)alloc((size_t)NN * 4);
    unsigned* offs     = (unsigned*)alloc((size_t)(NN + 1) * 4);
    unsigned* cursor   = (unsigned*)alloc((size_t)NN * 4);
    unsigned* chunkSum = (unsigned*)alloc((size_t)NCH * 4);
    unsigned* chunkOff = (unsigned*)alloc((size_t)NCH * 4);
    unsigned* posOf    = (unsigned*)alloc((size_t)EE * 4);
    unsigned* src_s    = (unsigned*)alloc((size_t)EE * 4);
    unsigned* dst_s    = (unsigned*)alloc((size_t)EE * 4);
    float2*   ae1s     = (float2*)alloc((size_t)EE * 8);
    float2*   ae2s     = (float2*)alloc((size_t)EE * 8);
    float2*   ap       = (float2*)alloc((size_t)EE * 8);
    float*    asrc     = (float*)alloc((size_t)NN * 8);
    float*    adst     = (float*)alloc((size_t)NN * 8);
    float*    hbuf     = (float*)alloc((size_t)NN * 128 * 4);
    float*    mid      = (float*)alloc((size_t)NN * 64 * 4);
    float*    rn1      = (float*)alloc((size_t)NN * 4);
    float*    rn2      = (float*)alloc((size_t)NN * 4);
    float*    Wq1      = (float*)alloc(8192 * 4);
    float*    Wq2      = (float*)alloc(8192 * 4);
    float*    v1       = (float*)alloc(64 * 4);
    float*    v2       = (float*)alloc(64 * 4);
    unsigned* slots1   = (unsigned*)alloc(256 * 4);
    unsigned* slots2   = (unsigned*)alloc(256 * 4);
    float*    s1       = (float*)alloc(4);
    float*    s2       = (float*)alloc(4);

    dim3 B(256);
    k_init<<<391, B, 0, stream>>>(deg_src, deg_dst, slots1, slots2);
    k_deg<<<3125, B, 0, stream>>>(ei, deg_src, deg_dst);
    k_scan_chunksum<<<NCH, B, 0, stream>>>(deg_dst, chunkSum);
    k_scan_chunkoff<<<1, B, 0, stream>>>(chunkSum, chunkOff, offs);
    k_scan_final<<<NCH, B, 0, stream>>>(deg_dst, chunkOff, offs, cursor);
    k_scatter<<<3125, B, 0, stream>>>(ei, cursor, posOf, src_s, dst_s);
    k_rnorm<<<391, B, 0, stream>>>(deg_src, a1, a2, rn1, rn2);
    k_weights<<<1, B, 0, stream>>>(W1, W2, We1, ae1, We2, ae2, Wq1, Wq2, v1, v2);
    k_aedge<<<3125, B, 0, stream>>>(eattr, v1, v2, posOf, ae1s, ae2s);
    // layer 1
    k_hproj<<<3125, B, 0, stream>>>(x, rn1, Wq1, as1, ad1, hbuf, asrc, adst);
    k_alphap<<<3125, B, 0, stream>>>(src_s, dst_s, asrc, adst, ae1s, ap);
    k_aggregate<<<25000, B, 0, stream>>>(offs, src_s, ap, hbuf, b1, mid, slots1);
    k_amax_reduce<<<1, B, 0, stream>>>(slots1, s1);
    k_quant_relu_norm<<<25000, B, 0, stream>>>(mid, s1, rn2);
    // layer 2
    k_hproj<<<3125, B, 0, stream>>>(mid, nullptr, Wq2, as2, ad2, hbuf, asrc, adst);
    k_alphap<<<3125, B, 0, stream>>>(src_s, dst_s, asrc, adst, ae2s, ap);
    k_aggregate<<<25000, B, 0, stream>>>(offs, src_s, ap, hbuf, b2, out, slots2);
    k_amax_reduce<<<1, B, 0, stream>>>(slots2, s2);
    k_quant_out<<<25000, B, 0, stream>>>(out, s2);
}